// Round 1
// baseline (1169.101 us; speedup 1.0000x reference)
//
#include <hip/hip_runtime.h>

#define BB 16
#define CC 256
#define FF 30000
#define TGT 15000

// -------- pass 1: per-batch histogram of group ids ----------
__global__ __launch_bounds__(256) void count_kernel(const int* __restrict__ gid,
                                                    int* __restrict__ counts) {
    const int f = blockIdx.x * 256 + threadIdx.x;
    const int b = blockIdx.y;
    if (f < FF) {
        const int g = gid[b * FF + f];
        atomicAdd(&counts[b * TGT + g], 1);
    }
}

// -------- pass 2: one block per (b, c); LDS scatter-accumulate ----------
__global__ __launch_bounds__(512, 4) void pool_kernel(const float* __restrict__ fe,
                                                      const int* __restrict__ gid,
                                                      const int* __restrict__ counts,
                                                      float* __restrict__ out) {
    __shared__ __align__(16) float smem[TGT];

    const int tid = threadIdx.x;
    const int c = blockIdx.x;
    const int b = blockIdx.y;

    // zero the LDS accumulator (vectorized)
    float4* smem4 = reinterpret_cast<float4*>(smem);
    #pragma unroll 2
    for (int i = tid; i < TGT / 4; i += 512) {
        smem4[i] = make_float4(0.f, 0.f, 0.f, 0.f);
    }
    __syncthreads();

    // stream the face-feature row, scatter into LDS with ds-atomics
    const float4* fe4 = reinterpret_cast<const float4*>(fe + ((size_t)b * CC + c) * FF);
    const int4*   g4  = reinterpret_cast<const int4*>(gid + (size_t)b * FF);

    for (int i = tid; i < FF / 4; i += 512) {
        const float4 v = fe4[i];
        const int4   g = g4[i];
        atomicAdd(&smem[g.x], v.x);
        atomicAdd(&smem[g.y], v.y);
        atomicAdd(&smem[g.z], v.z);
        atomicAdd(&smem[g.w], v.w);
    }
    __syncthreads();

    // epilogue: divide by counts, coalesced float4 store
    const int4* cnt4 = reinterpret_cast<const int4*>(counts + (size_t)b * TGT);
    float4* out4 = reinterpret_cast<float4*>(out + ((size_t)b * CC + c) * TGT);

    for (int i = tid; i < TGT / 4; i += 512) {
        const float4 s = smem4[i];
        const int4   n = cnt4[i];
        float4 r;
        r.x = s.x / fmaxf((float)n.x, 1.f);
        r.y = s.y / fmaxf((float)n.y, 1.f);
        r.z = s.z / fmaxf((float)n.z, 1.f);
        r.w = s.w / fmaxf((float)n.w, 1.f);
        out4[i] = r;
    }
}

extern "C" void kernel_launch(void* const* d_in, const int* in_sizes, int n_in,
                              void* d_out, int out_size, void* d_ws, size_t ws_size,
                              hipStream_t stream) {
    const float* fe  = (const float*)d_in[0];   // [B, C, F] f32
    const int*   gid = (const int*)d_in[1];     // [B, F] int32
    float* out = (float*)d_out;                  // [B, C, TGT] f32
    int* counts = (int*)d_ws;                    // [B, TGT] int32 scratch

    // ws is re-poisoned before every launch — zero the histogram each call
    hipMemsetAsync(counts, 0, (size_t)BB * TGT * sizeof(int), stream);

    dim3 cgrid((FF + 255) / 256, BB);
    count_kernel<<<cgrid, 256, 0, stream>>>(gid, counts);

    dim3 pgrid(CC, BB);
    pool_kernel<<<pgrid, 512, 0, stream>>>(fe, gid, counts, out);
}

// Round 2
// 985.921 us; speedup vs baseline: 1.1858x; 1.1858x over previous
//
#include <hip/hip_runtime.h>

#define BB 16
#define CC 256
#define FF 30000
#define TGT 15000
#define OSTR 15004   // offs row stride (ints), padded so each row is 16B-aligned

// workspace layout (ints):
//   counts : [BB * TGT]          at 0
//   offs   : [BB * OSTR]         at 240000      (offs[b][TGT] = FF sentinel)
//   cursor : [BB * TGT]          at 480064
//   perm   : [BB * FF]           at 720064
// total 1,200,064 ints = 4.8 MB

// -------- pass 1: per-batch histogram of group ids ----------
__global__ __launch_bounds__(256) void count_kernel(const int* __restrict__ gid,
                                                    int* __restrict__ counts) {
    const int f = blockIdx.x * 256 + threadIdx.x;
    const int b = blockIdx.y;
    if (f < FF) {
        const int g = gid[b * FF + f];
        atomicAdd(&counts[b * TGT + g], 1);
    }
}

// -------- pass 2: per-batch exclusive scan of counts -> offs, cursor ----------
__global__ __launch_bounds__(1024) void scan_kernel(const int* __restrict__ counts,
                                                    int* __restrict__ offs,
                                                    int* __restrict__ cursor) {
    const int b = blockIdx.x;
    const int t = threadIdx.x;
    const int PER = 15;                      // 1024*15 = 15360 >= TGT
    __shared__ int part[1024];

    int local[PER];
    int s = 0;
    const int base = t * PER;
    #pragma unroll
    for (int i = 0; i < PER; ++i) {
        const int g = base + i;
        const int c = (g < TGT) ? counts[b * TGT + g] : 0;
        local[i] = c;
        s += c;
    }
    part[t] = s;
    __syncthreads();

    // Hillis-Steele inclusive scan over 1024 partials
    for (int off = 1; off < 1024; off <<= 1) {
        const int v = (t >= off) ? part[t - off] : 0;
        __syncthreads();
        part[t] += v;
        __syncthreads();
    }
    int run = (t == 0) ? 0 : part[t - 1];    // exclusive prefix

    #pragma unroll
    for (int i = 0; i < PER; ++i) {
        const int g = base + i;
        if (g < TGT) {
            offs[b * OSTR + g] = run;
            cursor[b * TGT + g] = run;
            run += local[i];
        }
    }
    if (t == 1023) offs[b * OSTR + TGT] = FF;   // sentinel
}

// -------- pass 3: counting-sort scatter of face indices ----------
__global__ __launch_bounds__(256) void scatter_kernel(const int* __restrict__ gid,
                                                      int* __restrict__ cursor,
                                                      int* __restrict__ perm) {
    const int f = blockIdx.x * 256 + threadIdx.x;
    const int b = blockIdx.y;
    if (f < FF) {
        const int g = gid[b * FF + f];
        const int pos = atomicAdd(&cursor[b * TGT + g], 1);
        perm[b * FF + pos] = f;
    }
}

// -------- pass 4: one block per (b, c); LDS row stage + segmented gather ----------
__global__ __launch_bounds__(1024) void pool_kernel(const float* __restrict__ fe,
                                                    const int* __restrict__ offs,
                                                    const int* __restrict__ perm,
                                                    float* __restrict__ out) {
    __shared__ __align__(16) float row[FF];   // 120 KB: whole fe[b,c,:] row

    const int tid = threadIdx.x;
    const int c = blockIdx.x;
    const int b = blockIdx.y;

    // coalesced float4 stage of the feature row
    const float4* fe4 = reinterpret_cast<const float4*>(fe + ((size_t)b * CC + c) * FF);
    float4* row4 = reinterpret_cast<float4*>(row);
    for (int i = tid; i < FF / 4; i += 1024) {
        row4[i] = fe4[i];
    }
    __syncthreads();

    const int* ob = offs + b * OSTR;
    const int* pb = perm + (size_t)b * FF;
    float4* out4 = reinterpret_cast<float4*>(out + ((size_t)b * CC + c) * TGT);

    for (int i = tid; i < TGT / 4; i += 1024) {
        const int4 o = reinterpret_cast<const int4*>(ob)[i];  // offs[4i .. 4i+3]
        const int e4 = ob[4 * i + 4];                         // offs[4i+4]
        float s0 = 0.f, s1 = 0.f, s2 = 0.f, s3 = 0.f;
        for (int j = o.x; j < o.y; ++j) s0 += row[pb[j]];
        for (int j = o.y; j < o.z; ++j) s1 += row[pb[j]];
        for (int j = o.z; j < o.w; ++j) s2 += row[pb[j]];
        for (int j = o.w; j < e4;  ++j) s3 += row[pb[j]];
        float4 r;
        r.x = s0 / fmaxf((float)(o.y - o.x), 1.f);
        r.y = s1 / fmaxf((float)(o.z - o.y), 1.f);
        r.z = s2 / fmaxf((float)(o.w - o.z), 1.f);
        r.w = s3 / fmaxf((float)(e4 - o.w), 1.f);
        out4[i] = r;
    }
}

extern "C" void kernel_launch(void* const* d_in, const int* in_sizes, int n_in,
                              void* d_out, int out_size, void* d_ws, size_t ws_size,
                              hipStream_t stream) {
    const float* fe  = (const float*)d_in[0];   // [B, C, F] f32
    const int*   gid = (const int*)d_in[1];     // [B, F] int32
    float* out = (float*)d_out;                  // [B, C, TGT] f32

    int* ws      = (int*)d_ws;
    int* counts  = ws;                 // [BB*TGT]
    int* offs    = ws + 240000;        // [BB*OSTR]
    int* cursor  = ws + 480064;        // [BB*TGT]
    int* perm    = ws + 720064;        // [BB*FF]

    // counts must start at zero (ws is poisoned each call)
    hipMemsetAsync(counts, 0, (size_t)BB * TGT * sizeof(int), stream);

    dim3 fgrid((FF + 255) / 256, BB);
    count_kernel<<<fgrid, 256, 0, stream>>>(gid, counts);
    scan_kernel<<<dim3(BB), 1024, 0, stream>>>(counts, offs, cursor);
    scatter_kernel<<<fgrid, 256, 0, stream>>>(gid, cursor, perm);

    dim3 pgrid(CC, BB);
    pool_kernel<<<pgrid, 1024, 0, stream>>>(fe, offs, perm, out);
}